// Round 1
// baseline (124.219 us; speedup 1.0000x reference)
//
#include <hip/hip_runtime.h>
#include <hip/hip_bf16.h>
#include <math.h>

// Problem constants
#define N_NODES 600
#define N_EDGES 9600
#define HDIM    128
#define HA      256
#define HC      256
#define NN      (N_NODES*N_NODES)   // 360000
#define BN_EPS  1e-5f

// logits tiling
#define TI  32                       // block tile (i and j)
#define NTB (((N_NODES+TI-1)/TI)*((N_NODES+TI-1)/TI))  // 19*19 = 361 blocks
#define NSB ((NN+255)/256)           // 1407 blocks for exp/scale

// workspace layout (float offsets)
#define OFF_T0   0          // 1200   : x + agg (layer 0 input to MLP)
#define OFF_T1   1200       // 76800  : h0 + agg (layer 1 input to MLP)
#define OFF_R0   78000      // 76800  : relu(bn(h1)) layer 0
#define OFF_H0   154800     // 76800  : h after layer 0
#define OFF_R1   231600     // 76800  : relu(bn(h1)) layer 1
#define OFF_HH   308400     // 76800  : h after layer 1
#define OFF_HS   385200     // 256    : ge@Ws + a_b0
#define OFF_A    385456     // 153600 : hs + h@Wn1   (j,k)
#define OFF_B    539056     // 153600 : h@Wn2        (i,k)
#define OFF_LG   692656     // 360000 : logits
#define OFF_MAXA 1052656    // 512    : per-block maxes
#define OFF_SUMA 1053168    // 2048   : per-block sums
#define OFF_SCAL 1055216    // 8      : [0]=global max, [1]=1/sum

// ---------------- layer-0 aggregation ----------------
__global__ void k_init_t0(const float* __restrict__ feat, float* __restrict__ t0) {
  int i = threadIdx.x + blockIdx.x * blockDim.x;
  if (i < N_NODES * 2) t0[i] = feat[i];
}

__global__ void k_edges0(const int* __restrict__ ei, const float* __restrict__ feat,
                         float* __restrict__ t0) {
  int e = threadIdx.x + blockIdx.x * blockDim.x;
  if (e >= N_EDGES) return;
  int s = ei[e], d = ei[N_EDGES + e];
  atomicAdd(&t0[d * 2 + 0], feat[s * 2 + 0]);
  atomicAdd(&t0[d * 2 + 1], feat[s * 2 + 1]);
}

// ---------------- GIN layer 0: (t0 @ W0 + b0) -> BN -> relu, per-channel block ----------------
__global__ void k_gin0(const float* __restrict__ t0, const float* __restrict__ W0,
                       const float* __restrict__ b0, const float* __restrict__ gamma,
                       const float* __restrict__ beta, float* __restrict__ r0) {
  int j = blockIdx.x;     // output channel
  int t = threadIdx.x;    // 256 threads
  float w0 = W0[j], w1 = W0[HDIM + j], bb = b0[j];
  float v[3]; int nr = 0;
  float s = 0.f, s2 = 0.f;
  for (int q = 0; q < 3; q++) {
    int n = t + q * 256;
    if (n < N_NODES) {
      float x = t0[n * 2] * w0 + t0[n * 2 + 1] * w1 + bb;
      v[q] = x; s += x; s2 += x * x; nr = q + 1;
    }
  }
  __shared__ float ls[256], ls2[256];
  ls[t] = s; ls2[t] = s2;
  __syncthreads();
  for (int off = 128; off > 0; off >>= 1) {
    if (t < off) { ls[t] += ls[t + off]; ls2[t] += ls2[t + off]; }
    __syncthreads();
  }
  float mu  = ls[0] * (1.0f / N_NODES);
  float var = ls2[0] * (1.0f / N_NODES) - mu * mu;
  float g   = gamma[j] / sqrtf(var + BN_EPS);
  float be  = beta[j];
  for (int q = 0; q < nr; q++) {
    int n = t + q * 256;
    float y = (v[q] - mu) * g + be;
    r0[n * HDIM + j] = y > 0.f ? y : 0.f;
  }
}

// ---------------- r @ W1 + b1 (600x128 @ 128x128); optionally duplicate output ----------------
template <bool DUP>
__global__ void k_mm(const float* __restrict__ r, const float* __restrict__ W,
                     const float* __restrict__ b, float* __restrict__ out,
                     float* __restrict__ out2) {
  int idx = threadIdx.x + blockIdx.x * blockDim.x;
  if (idx >= N_NODES * HDIM) return;
  int n = idx >> 7, j = idx & 127;
  const float* row = r + n * HDIM;
  float acc = b[j];
#pragma unroll 8
  for (int k = 0; k < HDIM; k++) acc += row[k] * W[k * HDIM + j];
  out[idx] = acc;
  if (DUP) out2[idx] = acc;
}

// ---------------- layer-1 edge scatter: t1 += h0[src] (128 channels) ----------------
__global__ void k_edges1(const int* __restrict__ ei, const float* __restrict__ h0,
                         float* __restrict__ t1) {
  int idx = threadIdx.x + blockIdx.x * blockDim.x;  // E*32
  int e = idx >> 5, cg = (idx & 31) * 4;
  if (e >= N_EDGES) return;
  int s = ei[e], d = ei[N_EDGES + e];
  float4 v = *(const float4*)(h0 + s * HDIM + cg);
  float* p = t1 + d * HDIM + cg;
  atomicAdd(p + 0, v.x); atomicAdd(p + 1, v.y);
  atomicAdd(p + 2, v.z); atomicAdd(p + 3, v.w);
}

// ---------------- GIN layer 1: (t1 @ W0 + b0) -> BN -> relu ----------------
__global__ void k_gin1(const float* __restrict__ t1, const float* __restrict__ W0,
                       const float* __restrict__ b0, const float* __restrict__ gamma,
                       const float* __restrict__ beta, float* __restrict__ r1) {
  int j = blockIdx.x, t = threadIdx.x;
  __shared__ float wcol[HDIM];
  if (t < HDIM) wcol[t] = W0[t * HDIM + j];
  __syncthreads();
  float bb = b0[j];
  float v[3]; int nr = 0;
  float s = 0.f, s2 = 0.f;
  for (int q = 0; q < 3; q++) {
    int n = t + q * 256;
    if (n < N_NODES) {
      const float4* row = (const float4*)(t1 + n * HDIM);
      float acc = bb;
#pragma unroll
      for (int k4 = 0; k4 < HDIM / 4; k4++) {
        float4 rv = row[k4];
        acc += rv.x * wcol[k4 * 4 + 0] + rv.y * wcol[k4 * 4 + 1]
             + rv.z * wcol[k4 * 4 + 2] + rv.w * wcol[k4 * 4 + 3];
      }
      v[q] = acc; s += acc; s2 += acc * acc; nr = q + 1;
    }
  }
  __shared__ float ls[256], ls2[256];
  ls[t] = s; ls2[t] = s2;
  __syncthreads();
  for (int off = 128; off > 0; off >>= 1) {
    if (t < off) { ls[t] += ls[t + off]; ls2[t] += ls2[t + off]; }
    __syncthreads();
  }
  float mu  = ls[0] * (1.0f / N_NODES);
  float var = ls2[0] * (1.0f / N_NODES) - mu * mu;
  float g   = gamma[j] / sqrtf(var + BN_EPS);
  float be  = beta[j];
  for (int q = 0; q < nr; q++) {
    int n = t + q * 256;
    float y = (v[q] - mu) * g + be;
    r1[n * HDIM + j] = y > 0.f ? y : 0.f;
  }
}

// ---------------- head: ge = mean(h), value, hs = ge@Ws + a_b0 (one block, 256 threads) --------
__global__ void k_head(const float* __restrict__ h, const float* __restrict__ cW0,
                       const float* __restrict__ cb0, const float* __restrict__ cW1,
                       const float* __restrict__ cb1, const float* __restrict__ aW0,
                       const float* __restrict__ ab0, float* __restrict__ hs,
                       float* __restrict__ out_value) {
  __shared__ float ge[HDIM];
  __shared__ float red[256];
  int t = threadIdx.x;
  int c = t & 127, half = t >> 7;
  float s = 0.f;
  for (int n = half * 300; n < (half + 1) * 300; n++) s += h[n * HDIM + c];
  red[t] = s;
  __syncthreads();
  if (t < HDIM) ge[t] = (red[t] + red[t + 128]) * (1.0f / N_NODES);
  __syncthreads();
  float hv = cb0[t], ha = ab0[t];
  for (int cc = 0; cc < HDIM; cc++) {
    float g = ge[cc];
    hv += g * cW0[cc * HC + t];
    ha += g * aW0[cc * HA + t];   // Ws = a_W0 rows [0,128)
  }
  hs[t] = ha;
  hv = hv > 0.f ? hv : 0.f;
  red[t] = hv * cW1[t];
  __syncthreads();
  for (int off = 128; off > 0; off >>= 1) {
    if (t < off) red[t] += red[t + off];
    __syncthreads();
  }
  if (t == 0) *out_value = red[0] + cb1[0];
}

// ---------------- A[j,k] = hs[k] + (h@Wn1)[j,k]; B[i,k] = (h@Wn2)[i,k] ----------------
__global__ void k_ab(const float* __restrict__ h, const float* __restrict__ aW0,
                     const float* __restrict__ hs, float* __restrict__ A,
                     float* __restrict__ B) {
  int idx = threadIdx.x + blockIdx.x * blockDim.x;
  if (idx >= N_NODES * 2 * HA) return;
  int n = idx >> 9;          // node
  int m = idx & 511;         // 0..255 -> A, 256..511 -> B
  int k = m & 255;
  const float4* row = (const float4*)(h + n * HDIM);
  const float* Wb = aW0 + (m < HA ? HDIM * HA : 2 * HDIM * HA) + k;
  float acc = 0.f;
#pragma unroll
  for (int c4 = 0; c4 < HDIM / 4; c4++) {
    float4 rv = row[c4];
    acc += rv.x * Wb[(c4 * 4 + 0) * HA] + rv.y * Wb[(c4 * 4 + 1) * HA]
         + rv.z * Wb[(c4 * 4 + 2) * HA] + rv.w * Wb[(c4 * 4 + 3) * HA];
  }
  if (m < HA) A[n * HA + k] = acc + hs[k];
  else        B[n * HA + k] = acc;
}

// ---------------- logits[i*600+j] = sum_k relu(A[j,k]+B[i,k])*w[k]; block max ----------------
// 32x32 (i,j) tile per block, 256 threads, 2x2 per thread, LDS-staged k-chunks of 128.
#define KC 128
#define LPAD 130  // row stride (pad +2): 2-way bank aliasing only (free)
__global__ void k_logits(const float* __restrict__ A, const float* __restrict__ Bm,
                         const float* __restrict__ w, float* __restrict__ logits,
                         float* __restrict__ maxarr) {
  __shared__ float As[TI * LPAD];
  __shared__ float Bs[TI * LPAD];
  __shared__ float ws[HA];
  __shared__ float red[256];
  int t = threadIdx.x;
  int bj = blockIdx.x, bi = blockIdx.y;
  int i0 = bi * TI, j0 = bj * TI;
  int tx = t & 15, ty = t >> 4;
  int jl = tx * 2, il = ty * 2;
  ws[t] = w[t];  // HA==256==blockDim
  float a00 = 0.f, a01 = 0.f, a10 = 0.f, a11 = 0.f;
  for (int kc = 0; kc < HA; kc += KC) {
    __syncthreads();  // protect LDS from previous chunk readers / publish ws
    // stage 32x128 of A and B (vector global load, scalar LDS stores)
    for (int q = 0; q < 2; q++) {
      int f4  = q * 256 + t;        // 0..511
      int row = f4 >> 4;            // 32 rows, 16 float4 per... (128/4=32 -> use >>5)
      (void)row;
    }
    for (int q = 0; q < 4; q++) {
      int f4  = q * 256 + t;        // 0..1023 float4 slots (32 rows * 32 f4)
      int row = f4 >> 5;
      int c4  = (f4 & 31) * 4;
      float4 va = (j0 + row < N_NODES)
        ? *(const float4*)(A + (j0 + row) * HA + kc + c4) : make_float4(0, 0, 0, 0);
      float4 vb = (i0 + row < N_NODES)
        ? *(const float4*)(Bm + (i0 + row) * HA + kc + c4) : make_float4(0, 0, 0, 0);
      float* pa = &As[row * LPAD + c4];
      pa[0] = va.x; pa[1] = va.y; pa[2] = va.z; pa[3] = va.w;
      float* pb = &Bs[row * LPAD + c4];
      pb[0] = vb.x; pb[1] = vb.y; pb[2] = vb.z; pb[3] = vb.w;
    }
    __syncthreads();
#pragma unroll 4
    for (int k = 0; k < KC; k++) {
      float wk = ws[kc + k];
      float va0 = As[jl * LPAD + k], va1 = As[(jl + 1) * LPAD + k];
      float vb0 = Bs[il * LPAD + k], vb1 = Bs[(il + 1) * LPAD + k];
      float p00 = va0 + vb0, p01 = va1 + vb0, p10 = va0 + vb1, p11 = va1 + vb1;
      a00 += (p00 > 0.f ? p00 : 0.f) * wk;
      a01 += (p01 > 0.f ? p01 : 0.f) * wk;
      a10 += (p10 > 0.f ? p10 : 0.f) * wk;
      a11 += (p11 > 0.f ? p11 : 0.f) * wk;
    }
  }
  int gi = i0 + il, gj = j0 + jl;
  float m = -INFINITY;
  if (gi < N_NODES && gj < N_NODES)         { logits[gi * N_NODES + gj] = a00;           m = fmaxf(m, a00); }
  if (gi < N_NODES && gj + 1 < N_NODES)     { logits[gi * N_NODES + gj + 1] = a01;       m = fmaxf(m, a01); }
  if (gi + 1 < N_NODES && gj < N_NODES)     { logits[(gi + 1) * N_NODES + gj] = a10;     m = fmaxf(m, a10); }
  if (gi + 1 < N_NODES && gj + 1 < N_NODES) { logits[(gi + 1) * N_NODES + gj + 1] = a11; m = fmaxf(m, a11); }
  red[t] = m;
  __syncthreads();
  for (int off = 128; off > 0; off >>= 1) {
    if (t < off) red[t] = fmaxf(red[t], red[t + off]);
    __syncthreads();
  }
  if (t == 0) maxarr[bi * gridDim.x + bj] = red[0];
}

// ---------------- softmax finalize ----------------
__global__ void k_maxfin(const float* __restrict__ maxarr, float* __restrict__ scal) {
  __shared__ float red[512];
  int t = threadIdx.x;
  red[t] = (t < NTB) ? maxarr[t] : -INFINITY;
  __syncthreads();
  for (int off = 256; off > 0; off >>= 1) {
    if (t < off) red[t] = fmaxf(red[t], red[t + off]);
    __syncthreads();
  }
  if (t == 0) scal[0] = red[0];
}

__global__ void k_exp(const float* __restrict__ logits, const float* __restrict__ scal,
                      float* __restrict__ pi, float* __restrict__ sumarr) {
  __shared__ float red[256];
  int t = threadIdx.x;
  int idx = t + blockIdx.x * 256;
  float e = 0.f;
  float gmax = scal[0];
  if (idx < NN) { e = expf(logits[idx] - gmax); pi[idx] = e; }
  red[t] = e;
  __syncthreads();
  for (int off = 128; off > 0; off >>= 1) {
    if (t < off) red[t] += red[t + off];
    __syncthreads();
  }
  if (t == 0) sumarr[blockIdx.x] = red[0];
}

__global__ void k_sumfin(const float* __restrict__ sumarr, float* __restrict__ scal) {
  __shared__ float red[1024];
  int t = threadIdx.x;
  float s = 0.f;
  for (int i = t; i < NSB; i += 1024) s += sumarr[i];
  red[t] = s;
  __syncthreads();
  for (int off = 512; off > 0; off >>= 1) {
    if (t < off) red[t] += red[t + off];
    __syncthreads();
  }
  if (t == 0) scal[1] = 1.0f / red[0];
}

__global__ void k_scale(float* __restrict__ pi, const float* __restrict__ scal) {
  int idx = threadIdx.x + blockIdx.x * 256;
  if (idx < NN) pi[idx] *= scal[1];
}

// ---------------- launch ----------------
extern "C" void kernel_launch(void* const* d_in, const int* in_sizes, int n_in,
                              void* d_out, int out_size, void* d_ws, size_t ws_size,
                              hipStream_t stream) {
  const float* feat   = (const float*)d_in[0];
  const int*   ei     = (const int*)  d_in[1];
  const float* g0_W0  = (const float*)d_in[2];
  const float* g0_b0  = (const float*)d_in[3];
  const float* g0_ga  = (const float*)d_in[4];
  const float* g0_be  = (const float*)d_in[5];
  const float* g0_W1  = (const float*)d_in[6];
  const float* g0_b1  = (const float*)d_in[7];
  const float* g1_W0  = (const float*)d_in[8];
  const float* g1_b0  = (const float*)d_in[9];
  const float* g1_ga  = (const float*)d_in[10];
  const float* g1_be  = (const float*)d_in[11];
  const float* g1_W1  = (const float*)d_in[12];
  const float* g1_b1  = (const float*)d_in[13];
  const float* a_W0   = (const float*)d_in[14];
  const float* a_b0   = (const float*)d_in[15];
  const float* a_W1   = (const float*)d_in[16];
  // a_b1 (d_in[17]) shifts all logits equally -> cancels in softmax
  const float* c_W0   = (const float*)d_in[18];
  const float* c_b0   = (const float*)d_in[19];
  const float* c_W1   = (const float*)d_in[20];
  const float* c_b1   = (const float*)d_in[21];

  float* ws = (float*)d_ws;
  float* t0   = ws + OFF_T0;
  float* t1   = ws + OFF_T1;
  float* r0   = ws + OFF_R0;
  float* h0   = ws + OFF_H0;
  float* r1   = ws + OFF_R1;
  float* hh   = ws + OFF_HH;
  float* hs   = ws + OFF_HS;
  float* A    = ws + OFF_A;
  float* B    = ws + OFF_B;
  float* lg   = ws + OFF_LG;
  float* maxa = ws + OFF_MAXA;
  float* suma = ws + OFF_SUMA;
  float* scal = ws + OFF_SCAL;

  float* pi  = (float*)d_out;            // 360000
  float* val = (float*)d_out + NN;       // 1

  hipLaunchKernelGGL(k_init_t0, dim3(5), dim3(256), 0, stream, feat, t0);
  hipLaunchKernelGGL(k_edges0, dim3((N_EDGES + 255) / 256), dim3(256), 0, stream, ei, feat, t0);
  hipLaunchKernelGGL(k_gin0, dim3(HDIM), dim3(256), 0, stream, t0, g0_W0, g0_b0, g0_ga, g0_be, r0);
  hipLaunchKernelGGL((k_mm<true>), dim3(300), dim3(256), 0, stream, r0, g0_W1, g0_b1, h0, t1);
  hipLaunchKernelGGL(k_edges1, dim3(N_EDGES * 32 / 256), dim3(256), 0, stream, ei, h0, t1);
  hipLaunchKernelGGL(k_gin1, dim3(HDIM), dim3(256), 0, stream, t1, g1_W0, g1_b0, g1_ga, g1_be, r1);
  hipLaunchKernelGGL((k_mm<false>), dim3(300), dim3(256), 0, stream, r1, g1_W1, g1_b1, hh, (float*)nullptr);
  hipLaunchKernelGGL(k_head, dim3(1), dim3(256), 0, stream, hh, c_W0, c_b0, c_W1, c_b1, a_W0, a_b0, hs, val);
  hipLaunchKernelGGL(k_ab, dim3(N_NODES * 2 * HA / 256), dim3(256), 0, stream, hh, a_W0, hs, A, B);
  hipLaunchKernelGGL(k_logits, dim3(19, 19), dim3(256), 0, stream, A, B, a_W1, lg, maxa);
  hipLaunchKernelGGL(k_maxfin, dim3(1), dim3(512), 0, stream, maxa, scal);
  hipLaunchKernelGGL(k_exp, dim3(NSB), dim3(256), 0, stream, lg, scal, pi, suma);
  hipLaunchKernelGGL(k_sumfin, dim3(1), dim3(1024), 0, stream, suma, scal);
  hipLaunchKernelGGL(k_scale, dim3(NSB), dim3(256), 0, stream, pi, scal);
}